// Round 11
// baseline (341.574 us; speedup 1.0000x reference)
//
#include <hip/hip_runtime.h>

typedef __bf16 bf16;
typedef __bf16 bf16x8 __attribute__((ext_vector_type(8)));
typedef __bf16 bf16x4 __attribute__((ext_vector_type(4)));
typedef float  f32x4  __attribute__((ext_vector_type(4)));

#define GLD_LDS16(gp, lp) __builtin_amdgcn_global_load_lds( \
    (const __attribute__((address_space(1))) unsigned int*)(const void*)(gp), \
    (__attribute__((address_space(3))) unsigned int*)(void*)(lp), 16, 0, 0)

constexpr int BB = 4, SSEQ = 2048, DK = 1024, NH = 16, DH = 64;
constexpr int M = BB * SSEQ;                    // 8192 rows

constexpr size_t SZ_X = (size_t)M * DK * 2;     // 16 MiB
constexpr size_t SZ_W = (size_t)DK * DK * 2;    // 2 MiB
constexpr size_t OFF_WQT = 0;
constexpr size_t OFF_WKT = OFF_WQT + SZ_W;
constexpr size_t OFF_WVT = OFF_WKT + SZ_W;
constexpr size_t OFF_WUT = OFF_WVT + SZ_W;
constexpr size_t OFF_QH  = OFF_WUT + SZ_W;      // (B,S,1024) bf16 flat
constexpr size_t OFF_KH  = OFF_QH + SZ_X;       // (B,S,1024) bf16 flat
constexpr size_t OFF_VTH = OFF_KH + SZ_X;       // (B,H,64,S) bf16 (transposed)
constexpr size_t OFF_MRG = OFF_VTH + SZ_X;      // (B,S,1024) bf16

// ---------------------------------------------------------------- converts
__global__ void cvt_wT(const float* __restrict__ wq, const float* __restrict__ wk,
                       const float* __restrict__ wv, const float* __restrict__ wu,
                       bf16* __restrict__ wqt, bf16* __restrict__ wkt,
                       bf16* __restrict__ wvt, bf16* __restrict__ wut) {
    const float* w = (blockIdx.z == 0) ? wq : (blockIdx.z == 1) ? wk
                   : (blockIdx.z == 2) ? wv : wu;
    bf16* o        = (blockIdx.z == 0) ? wqt : (blockIdx.z == 1) ? wkt
                   : (blockIdx.z == 2) ? wvt : wut;
    __shared__ float t[64][65];
    int tx = threadIdx.x & 63, ty = threadIdx.x >> 6;
    int bx = blockIdx.x * 64, by = blockIdx.y * 64;
#pragma unroll
    for (int r = 0; r < 16; r++) {
        int row = ty * 16 + r;
        t[row][tx] = w[(size_t)(by + row) * DK + bx + tx];
    }
    __syncthreads();
#pragma unroll
    for (int r = 0; r < 16; r++) {
        int row2 = ty * 16 + r;
        o[(size_t)(bx + row2) * DK + by + tx] = (bf16)t[tx][row2];
    }
}

// ---------------------------------------------------------------- GEMM (C = A @ BT^T + bias)
// R7 schedule (verified race-free): 8-wave 128xBN x64 tile, raw s_barrier +
// counted vmcnt (T3+T4), T2 XOR-swizzle via pre-swizzled global source, T5
// setprio. Sync: BAR1 after vmcnt(N): tile t landed. BAR2 after lgkmcnt(0):
// all reads of buf[cur] retired -> stage(t+2) may overwrite.
// R11: AF32 variant — QKV GEMM reads A directly as f32 (q/k/v inputs), LDS
// A-tile stays f32 (64KB), conversion to bf16 happens at the LDS->frag read
// (scalar casts; compiler packs to cvt_pk, m240). Kills the cvt_x pass
// (144 MB of pure-conversion traffic, ~24us). Numerically identical (same
// f32->bf16 rounding, relocated). Stage = A4+B4 = 8 loads -> vmcnt(8).
// A-swizzle at 32B granularity: LDS slot s <- global slot s^(row&7) (involution).
// Proj keeps bf16 A path (AF32=false, vmcnt(4)).
// mode 0: out bf16 row-major; mode 1: out bf16 (B,H,64,S); mode 2: out f32
struct GArg {
    const void* A; const bf16* BT; const float* bias; void* out; int mode; float oscale;
};

template<int BNT, bool AF32>
__global__ __launch_bounds__(512, 2) void gemm_bt(GArg g0, GArg g1, GArg g2) {
    GArg g;
    if (blockIdx.z == 0) g = g0; else if (blockIdx.z == 1) g = g1; else g = g2;
    constexpr int JN = BNT / 64;                  // per-wave 16-col tiles (4 or 2)
    __shared__ __attribute__((aligned(16))) char AsRaw[2][128 * 64 * (AF32 ? 4 : 2)];
    __shared__ __attribute__((aligned(16))) bf16 Bs[2][BNT * 64];
    const int tid = threadIdx.x;                 // 0..511
    const int lane = tid & 63, wv = tid >> 6;    // 8 waves
    const int wm = (wv >> 2) * 64;               // 0,64   (2 row-groups)
    const int wn = (wv & 3) * (BNT / 4);         // 4 col-groups
    const int cl = lane & 15, qd = lane >> 4;
    const int x = (int)blockIdx.x;
    const int rowbase = ((x & 7) * 8 + ((x >> 3) & 7)) * 128;
    const int colbase = (x >> 6) * BNT;

    f32x4 acc[4][JN];
#pragma unroll
    for (int i = 0; i < 4; i++)
#pragma unroll
        for (int j = 0; j < JN; j++) acc[i][j] = f32x4{0.f, 0.f, 0.f, 0.f};

    const bool swapped = (g.mode == 1);

    auto stage = [&](int t, int buf) {
        if constexpr (AF32) {
            const float* Af = (const float*)g.A;
            // A tile f32 32KB: 2048 chunks of 16B. chunk -> (row = L>>4, s16 = L&15).
            // 32B slot s = s16>>1; source slot = s ^ (row&7) (pre-swizzled source).
#pragma unroll
            for (int c = 0; c < 4; c++) {
                int L = c * 512 + tid;
                int row = L >> 4, s16 = L & 15;
                int scol = (((s16 >> 1) ^ (row & 7)) * 2 + (s16 & 1)) * 4;   // f32 col
                GLD_LDS16(Af + (size_t)(rowbase + row) * DK + t * 64 + scol,
                          &AsRaw[buf][L * 16]);
            }
        } else {
            const bf16* Ab = (const bf16*)g.A;
#pragma unroll
            for (int c = 0; c < 2; c++) {
                int L = c * 512 + tid;
                int row = L >> 3, s16 = L & 7;
                int sc = s16 ^ (row & 7);
                GLD_LDS16(Ab + (size_t)(rowbase + row) * DK + t * 64 + sc * 8,
                          &AsRaw[buf][L * 16]);
            }
        }
#pragma unroll
        for (int c = 0; c < BNT / 64; c++) {
            int L = c * 512 + tid;
            int row = L >> 3, s16 = L & 7;
            int sc = s16 ^ (row & 7);
            GLD_LDS16(g.BT + (size_t)(colbase + row) * DK + t * 64 + sc * 8, &Bs[buf][L * 8]);
        }
    };

    stage(0, 0);
    stage(1, 1);

    // A fragment read: k-half h in {0,1}, row-tile i. row&7 == cl&7.
    auto ldA = [&](int cur, int i, int h) -> bf16x8 {
        int row = wm + i * 16 + cl;
        if constexpr (AF32) {
            const float* As = (const float*)AsRaw[cur];
            int slot = (h * 4 + qd) ^ (cl & 7);
            const float* p = &As[row * 64 + slot * 8];
            f32x4 lo = *(const f32x4*)p;
            f32x4 hi = *(const f32x4*)(p + 4);
            bf16x8 r;
#pragma unroll
            for (int e = 0; e < 4; e++) { r[e] = (bf16)lo[e]; r[4 + e] = (bf16)hi[e]; }
            return r;
        } else {
            const bf16* As = (const bf16*)AsRaw[cur];
            return *(const bf16x8*)&As[row * 64 + (((h * 4 + qd) ^ (cl & 7)) * 8)];
        }
    };

    auto ktile = [&](int t, int cur, bool doStage, bool last) __attribute__((always_inline)) {
        if (last) asm volatile("s_waitcnt vmcnt(0)" ::: "memory");
        else if constexpr (AF32)       asm volatile("s_waitcnt vmcnt(8)" ::: "memory");
        else if constexpr (BNT == 256) asm volatile("s_waitcnt vmcnt(6)" ::: "memory");
        else                           asm volatile("s_waitcnt vmcnt(4)" ::: "memory");
        asm volatile("s_barrier" ::: "memory");          // tile t visible everywhere
        bf16x8 a0[4], b0[JN], a1[4], b1[JN];
#pragma unroll
        for (int i = 0; i < 4; i++) a0[i] = ldA(cur, i, 0);
#pragma unroll
        for (int j = 0; j < JN; j++)
            b0[j] = *(const bf16x8*)&Bs[cur][(wn + j * 16 + cl) * 64 + ((qd ^ (cl & 7)) * 8)];
#pragma unroll
        for (int i = 0; i < 4; i++) a1[i] = ldA(cur, i, 1);
#pragma unroll
        for (int j = 0; j < JN; j++)
            b1[j] = *(const bf16x8*)&Bs[cur][(wn + j * 16 + cl) * 64 + (((4 + qd) ^ (cl & 7)) * 8)];
        __builtin_amdgcn_s_setprio(1);
        if (swapped) {
#pragma unroll
            for (int i = 0; i < 4; i++)
#pragma unroll
                for (int j = 0; j < JN; j++)
                    acc[i][j] = __builtin_amdgcn_mfma_f32_16x16x32_bf16(b0[j], a0[i], acc[i][j], 0, 0, 0);
        } else {
#pragma unroll
            for (int i = 0; i < 4; i++)
#pragma unroll
                for (int j = 0; j < JN; j++)
                    acc[i][j] = __builtin_amdgcn_mfma_f32_16x16x32_bf16(a0[i], b0[j], acc[i][j], 0, 0, 0);
        }
        __builtin_amdgcn_s_setprio(0);
        asm volatile("s_waitcnt lgkmcnt(0)" ::: "memory");  // ALL reads of buf[cur] retired
        asm volatile("s_barrier" ::: "memory");             // buffer free for restage
        if (doStage) stage(t + 2, cur);                     // in flight during k1 MFMAs
        __builtin_amdgcn_s_setprio(1);
        if (swapped) {
#pragma unroll
            for (int i = 0; i < 4; i++)
#pragma unroll
                for (int j = 0; j < JN; j++)
                    acc[i][j] = __builtin_amdgcn_mfma_f32_16x16x32_bf16(b1[j], a1[i], acc[i][j], 0, 0, 0);
        } else {
#pragma unroll
            for (int i = 0; i < 4; i++)
#pragma unroll
                for (int j = 0; j < JN; j++)
                    acc[i][j] = __builtin_amdgcn_mfma_f32_16x16x32_bf16(a1[i], b1[j], acc[i][j], 0, 0, 0);
        }
        __builtin_amdgcn_s_setprio(0);
    };

    for (int t = 0; t < 14; ++t) ktile(t, t & 1, true, false);
    ktile(14, 0, false, false);
    ktile(15, 1, false, true);

    if (g.mode == 2) {
        float* out = (float*)g.out;
#pragma unroll
        for (int i = 0; i < 4; i++)
#pragma unroll
            for (int j = 0; j < JN; j++)
#pragma unroll
                for (int r = 0; r < 4; r++) {
                    int row = rowbase + wm + i * 16 + qd * 4 + r;
                    int col = colbase + wn + j * 16 + cl;
                    out[(size_t)row * DK + col] = (acc[i][j][r] + g.bias[col]) * g.oscale;
                }
    } else if (g.mode == 0) {
        bf16* out = (bf16*)g.out;
#pragma unroll
        for (int i = 0; i < 4; i++)
#pragma unroll
            for (int j = 0; j < JN; j++)
#pragma unroll
                for (int r = 0; r < 4; r++) {
                    int row = rowbase + wm + i * 16 + qd * 4 + r;
                    int col = colbase + wn + j * 16 + cl;
                    float v = (acc[i][j][r] + g.bias[col]) * g.oscale;
                    out[(size_t)row * DK + col] = (bf16)v;
                }
    } else {
        // transposed epilogue: acc holds C^T tile — rows = cols(h,d), cols = rows(s)
        bf16* out = (bf16*)g.out;   // (B,H,64,S)
#pragma unroll
        for (int i = 0; i < 4; i++)
#pragma unroll
            for (int j = 0; j < JN; j++)
#pragma unroll
                for (int r = 0; r < 4; r++) {
                    int colg = colbase + wn + j * 16 + qd * 4 + r;   // h*64+d
                    int rowg = rowbase + wm + i * 16 + cl;           // b*2048+s
                    int b_ = rowg >> 11, s_ = rowg & 2047;
                    float v = (acc[i][j][r] + g.bias[colg]) * g.oscale;
                    out[((size_t)(b_ * NH + (colg >> 6)) * DH + (colg & 63)) * SSEQ + s_] = (bf16)v;
                }
    }
}

// ---------------------------------------------------------------- flash attention
// R10 version (measured 74.0us): grid 1024 (XCD-swizzled), 4 waves x 32 queries.
// S^T = K·Q^T via 16x16x32; KEY-PERMUTED K staging -> post-exp2 P fragments are
// directly the full-rate PV B-operand. Ones-MFMA softmax denominator (La) on
// the matrix pipe (VALU 50->44%); T5 setprio; bounds(256,3) — (256,4) spills.
__global__ __launch_bounds__(256, 3) void attn(const bf16* __restrict__ Qh,
                                               const bf16* __restrict__ Kh,
                                               const bf16* __restrict__ VTh,
                                               bf16* __restrict__ mrg) {
    __shared__ __attribute__((aligned(16))) bf16 Ks[2][64 * 64];   // [perm key][d], swizzled
    __shared__ __attribute__((aligned(16))) bf16 VTs[2][64 * 64];  // [d][key], swizzled
    const int tid = threadIdx.x;
    const int lane = tid & 63, w = tid >> 6;
    const int cl = lane & 15, qd = lane >> 4;
    // XCD swizzle: 8 bh values per XCD -> K/V working set = 4 MB = one L2
    const int F = blockIdx.x;            // 0..1023
    const int xcd = F & 7, slot = F >> 3;
    const int bh = xcd * 8 + (slot & 7);
    const int qt = slot >> 3;            // 0..15
    const int b_ = bh >> 4, h_ = bh & 15;
    const int qbase = qt * 128;
    const bf16* Qb = Qh + ((size_t)b_ * SSEQ) * DK + h_ * DH;   // row stride DK
    const bf16* Kb = Kh + ((size_t)b_ * SSEQ) * DK + h_ * DH;
    const bf16* Vb = VTh + (size_t)bh * DH * SSEQ;

    // Q fragments (B-operand of S^T): lane n=cl=query, k=d. Pre-scaled by log2(e)/8.
    bf16x8 qf[2][2];
#pragma unroll
    for (int mi = 0; mi < 2; mi++) {
        int q = qbase + w * 32 + mi * 16 + cl;
        qf[mi][0] = *(const bf16x8*)&Qb[(size_t)q * DK + qd * 8];
        qf[mi][1] = *(const bf16x8*)&Qb[(size_t)q * DK + 32 + qd * 8];
    }
    f32x4 O[2][4];   // O^T tiles: [query-tile][d-tile], lane: query=cl, d=qd*4+r
#pragma unroll
    for (int mi = 0; mi < 2; mi++)
#pragma unroll
        for (int jv = 0; jv < 4; jv++) O[mi][jv] = f32x4{0.f, 0.f, 0.f, 0.f};
    f32x4 La[2] = { f32x4{0.f, 0.f, 0.f, 0.f}, f32x4{0.f, 0.f, 0.f, 0.f} };
    bf16x8 ones8;
#pragma unroll
    for (int r = 0; r < 8; r++) ones8[r] = (bf16)1.0f;

    // stage tile kt into buffer buf. K rows permuted by pi; V unpermuted.
    auto stage = [&](int kt, int buf) {
#pragma unroll
        for (int c = 0; c < 2; c++) {
            int L = c * 256 + tid;
            int row = L >> 3, lc = (L & 7) ^ (row & 7);
            int prow = ((row >> 5) << 5) | (((row >> 2) & 3) << 3)
                     | (((row >> 4) & 1) << 2) | (row & 3);      // pi(row)
            GLD_LDS16(Kb + (size_t)(kt * 64 + prow) * DK + lc * 8, &Ks[buf][L * 8]);
        }
#pragma unroll
        for (int c = 0; c < 2; c++) {
            int L = c * 256 + tid;
            int row = L >> 3, lc = (L & 7) ^ (row & 7);
            GLD_LDS16(Vb + (size_t)row * SSEQ + kt * 64 + lc * 8, &VTs[buf][L * 8]);
        }
    };
    stage(0, 0);

    for (int kt = 0; kt < 32; kt++) {
        const int buf = kt & 1;
        __syncthreads();                 // tile kt staged; prev reads of buf^1 done
        if (kt + 1 < 32) stage(kt + 1, buf ^ 1);

        // S^T = K Q^T, exp2 -> P^T register fragments.
        // pf8[mi][g][ (jt&1)*4 + r ] = P[phys 32g+8qd+4*(jt&1)+r][query cl]
        bf16x8 pf8[2][2];
#pragma unroll
        for (int jt = 0; jt < 4; jt++) {
            bf16x8 kf0 = *(const bf16x8*)&Ks[buf][(jt * 16 + cl) * 64 + ((qd ^ (cl & 7)) * 8)];
            bf16x8 kf1 = *(const bf16x8*)&Ks[buf][(jt * 16 + cl) * 64 + (((4 + qd) ^ (cl & 7)) * 8)];
#pragma unroll
            for (int mi = 0; mi < 2; mi++) {
                __builtin_amdgcn_s_setprio(1);
                f32x4 S = __builtin_amdgcn_mfma_f32_16x16x32_bf16(kf0, qf[mi][0],
                                                                  f32x4{0.f, 0.f, 0.f, 0.f}, 0, 0, 0);
                S = __builtin_amdgcn_mfma_f32_16x16x32_bf16(kf1, qf[mi][1], S, 0, 0, 0);
                __builtin_amdgcn_s_setprio(0);
#pragma unroll
                for (int r = 0; r < 4; r++)
                    pf8[mi][jt >> 1][(jt & 1) * 4 + r] = (bf16)__builtin_amdgcn_exp2f(S[r]);
            }
        }

        // O^T += V^T P^T; l += ones·P^T (denominator on the matrix pipe)
        __builtin_amdgcn_s_setprio(1);
#pragma unroll
        for (int g = 0; g < 2; g++) {
#pragma unroll
            for (int jv = 0; jv < 4; jv++) {
                bf16x8 vf = *(const bf16x8*)&VTs[buf][(jv * 16 + cl) * 64 +
                                (((g * 4 + qd) ^ (cl & 7)) * 8)];
#pragma unroll
                for (int mi = 0; mi < 2; mi++)
                    O[mi][jv] = __builtin_amdgcn_mfma_f32_16x16x32_bf16(vf, pf8[mi][g], O[mi][jv], 0, 0, 0);
            }
#pragma unroll
            for (int mi = 0; mi < 2; mi++)
                La[mi] = __builtin_amdgcn_mfma_f32_16x16x32_bf16(ones8, pf8[mi][g], La[mi], 0, 0, 0);
        }
        __builtin_amdgcn_s_setprio(0);
    }

    // epilogue: every lane already holds l(query cl) in La[mi][0] — no shfl.
#pragma unroll
    for (int mi = 0; mi < 2; mi++) {
        float inv = 1.0f / La[mi][0];
        int q = qbase + w * 32 + mi * 16 + cl;
        size_t ro = ((size_t)(b_ * SSEQ + q)) * DK + h_ * DH;
#pragma unroll
        for (int jv = 0; jv < 4; jv++) {
            bf16x4 o4;
#pragma unroll
            for (int r = 0; r < 4; r++) o4[r] = (bf16)(O[mi][jv][r] * inv);
            *(bf16x4*)&mrg[ro + jv * 16 + qd * 4] = o4;
        }
    }
}

// ---------------------------------------------------------------- launch
extern "C" void kernel_launch(void* const* d_in, const int* in_sizes, int n_in,
                              void* d_out, int out_size, void* d_ws, size_t ws_size,
                              hipStream_t stream) {
    const float* q  = (const float*)d_in[0];
    const float* k  = (const float*)d_in[1];
    const float* v  = (const float*)d_in[2];
    const float* Wq = (const float*)d_in[3];
    const float* bq = (const float*)d_in[4];
    const float* Wk = (const float*)d_in[5];
    const float* bk = (const float*)d_in[6];
    const float* Wv = (const float*)d_in[7];
    const float* bv = (const float*)d_in[8];
    const float* Wu = (const float*)d_in[9];
    const float* bu = (const float*)d_in[10];
    char* ws = (char*)d_ws;
    bf16* wqt = (bf16*)(ws + OFF_WQT);
    bf16* wkt = (bf16*)(ws + OFF_WKT);
    bf16* wvt = (bf16*)(ws + OFF_WVT);
    bf16* wut = (bf16*)(ws + OFF_WUT);
    bf16* qh  = (bf16*)(ws + OFF_QH);
    bf16* kh  = (bf16*)(ws + OFF_KH);
    bf16* vth = (bf16*)(ws + OFF_VTH);
    bf16* mrg = (bf16*)(ws + OFF_MRG);

    cvt_wT<<<dim3(16, 16, 4), 256, 0, stream>>>(Wq, Wk, Wv, Wu, wqt, wkt, wvt, wut);

    // Q projection folds score scale AND log2(e) for exp2-softmax: 0.125 * log2(e)
    GArg gq{(const void*)q, wqt, bq, (void*)qh, 0, 0.18033688011112043f};
    GArg gk{(const void*)k, wkt, bk, (void*)kh, 0, 1.0f};
    GArg gv{(const void*)v, wvt, bv, (void*)vth, 1, 1.0f};
    gemm_bt<256, true><<<dim3(256, 1, 3), 512, 0, stream>>>(gq, gk, gv);

    attn<<<dim3(1024), 256, 0, stream>>>(qh, kh, vth, mrg);

    GArg go{(const void*)mrg, wut, bu, d_out, 2, 1.0f};
    gemm_bt<128, false><<<dim3(512, 1, 1), 512, 0, stream>>>(go, go, go);
}

// Round 12
// 334.399 us; speedup vs baseline: 1.0215x; 1.0215x over previous
//
#include <hip/hip_runtime.h>

typedef __bf16 bf16;
typedef __bf16 bf16x8 __attribute__((ext_vector_type(8)));
typedef __bf16 bf16x4 __attribute__((ext_vector_type(4)));
typedef float  f32x4  __attribute__((ext_vector_type(4)));

#define GLD_LDS16(gp, lp) __builtin_amdgcn_global_load_lds( \
    (const __attribute__((address_space(1))) unsigned int*)(const void*)(gp), \
    (__attribute__((address_space(3))) unsigned int*)(void*)(lp), 16, 0, 0)

constexpr int BB = 4, SSEQ = 2048, DK = 1024, NH = 16, DH = 64;
constexpr int M = BB * SSEQ;                    // 8192 rows

constexpr size_t SZ_X = (size_t)M * DK * 2;     // 16 MiB
constexpr size_t SZ_W = (size_t)DK * DK * 2;    // 2 MiB
constexpr size_t OFF_QBF = 0;
constexpr size_t OFF_KBF = OFF_QBF + SZ_X;
constexpr size_t OFF_VBF = OFF_KBF + SZ_X;
constexpr size_t OFF_WQT = OFF_VBF + SZ_X;
constexpr size_t OFF_WKT = OFF_WQT + SZ_W;
constexpr size_t OFF_WVT = OFF_WKT + SZ_W;
constexpr size_t OFF_WUT = OFF_WVT + SZ_W;
constexpr size_t OFF_QH  = OFF_WUT + SZ_W;      // (B,S,1024) bf16 flat
constexpr size_t OFF_KH  = OFF_QH + SZ_X;       // (B,S,1024) bf16 flat
constexpr size_t OFF_VTH = OFF_KH + SZ_X;       // (B,H,64,S) bf16 (transposed)
constexpr size_t OFF_MRG = OFF_VTH + SZ_X;      // (B,S,1024) bf16

// ---------------------------------------------------------------- converts
__global__ void cvt_x(const float* __restrict__ q, const float* __restrict__ k,
                      const float* __restrict__ v,
                      bf16* __restrict__ qb, bf16* __restrict__ kb, bf16* __restrict__ vb) {
    const float* s = (blockIdx.z == 0) ? q : (blockIdx.z == 1) ? k : v;
    bf16*        d = (blockIdx.z == 0) ? qb : (blockIdx.z == 1) ? kb : vb;
    size_t i = (size_t)blockIdx.x * blockDim.x + threadIdx.x;
    float4 val = ((const float4*)s)[i];
    bf16x4 o = { (bf16)val.x, (bf16)val.y, (bf16)val.z, (bf16)val.w };
    ((bf16x4*)d)[i] = o;
}

__global__ void cvt_wT(const float* __restrict__ wq, const float* __restrict__ wk,
                       const float* __restrict__ wv, const float* __restrict__ wu,
                       bf16* __restrict__ wqt, bf16* __restrict__ wkt,
                       bf16* __restrict__ wvt, bf16* __restrict__ wut) {
    const float* w = (blockIdx.z == 0) ? wq : (blockIdx.z == 1) ? wk
                   : (blockIdx.z == 2) ? wv : wu;
    bf16* o        = (blockIdx.z == 0) ? wqt : (blockIdx.z == 1) ? wkt
                   : (blockIdx.z == 2) ? wvt : wut;
    __shared__ float t[64][65];
    int tx = threadIdx.x & 63, ty = threadIdx.x >> 6;
    int bx = blockIdx.x * 64, by = blockIdx.y * 64;
#pragma unroll
    for (int r = 0; r < 16; r++) {
        int row = ty * 16 + r;
        t[row][tx] = w[(size_t)(by + row) * DK + bx + tx];
    }
    __syncthreads();
#pragma unroll
    for (int r = 0; r < 16; r++) {
        int row2 = ty * 16 + r;
        o[(size_t)(bx + row2) * DK + by + tx] = (bf16)t[tx][row2];
    }
}

// ---------------------------------------------------------------- GEMM (C = A @ BT^T + bias)
// R7 schedule (verified race-free): 8-wave 128xBN x64 tile, raw s_barrier +
// counted vmcnt (T3+T4), T2 XOR-swizzle via pre-swizzled global source, T5
// setprio. Sync: BAR1 after counted vmcnt: tile t landed. BAR2 after lgkm(0):
// all reads of buf[t%3] retired -> stage(t+3) may overwrite it.
// R11 LESSON: AF32 A-fusion regressed 2x (32B-granular swizzle = 16-bank
// spread + doubled staging bytes) — cvt_x stays a separate pass.
// R12: TRIPLE-buffered LDS. QKV runs 1 block/CU (96->144KB, occupancy
// unchanged — free): no cross-block TLP covers the BAR1 load-wait, so give
// loads 2 full ktiles in flight: steady vmcnt(2*LOADS), tail drain
// 2L -> L -> 0 (the 8-phase template's counted-drain pattern).
// QKV: BN=256, LOADS=6, vmcnt(12/6/0). Proj: BN=128, LOADS=4, vmcnt(8/4/0).
// mode 0: out bf16 row-major; mode 1: out bf16 (B,H,64,S); mode 2: out f32
struct GArg {
    const bf16* A; const bf16* BT; const float* bias; void* out; int mode; float oscale;
};

template<int BNT>
__global__ __launch_bounds__(512, 2) void gemm_bt(GArg g0, GArg g1, GArg g2) {
    GArg g;
    if (blockIdx.z == 0) g = g0; else if (blockIdx.z == 1) g = g1; else g = g2;
    constexpr int JN = BNT / 64;                  // per-wave 16-col tiles (4 or 2)
    constexpr int LOADS = 2 + BNT / 64;           // staging loads per thread per tile
    __shared__ __attribute__((aligned(16))) bf16 As[3][128 * 64];
    __shared__ __attribute__((aligned(16))) bf16 Bs[3][BNT * 64];
    const int tid = threadIdx.x;                 // 0..511
    const int lane = tid & 63, wv = tid >> 6;    // 8 waves
    const int wm = (wv >> 2) * 64;               // 0,64   (2 row-groups)
    const int wn = (wv & 3) * (BNT / 4);         // 4 col-groups
    const int cl = lane & 15, qd = lane >> 4;
    const int x = (int)blockIdx.x;
    const int rowbase = ((x & 7) * 8 + ((x >> 3) & 7)) * 128;
    const int colbase = (x >> 6) * BNT;

    f32x4 acc[4][JN];
#pragma unroll
    for (int i = 0; i < 4; i++)
#pragma unroll
        for (int j = 0; j < JN; j++) acc[i][j] = f32x4{0.f, 0.f, 0.f, 0.f};

    const bool swapped = (g.mode == 1);

    auto stage = [&](int t, int buf) {
#pragma unroll
        for (int c = 0; c < 2; c++) {
            int L = c * 512 + tid;
            int row = L >> 3, s16 = L & 7;
            int sc = s16 ^ (row & 7);
            GLD_LDS16(g.A + (size_t)(rowbase + row) * DK + t * 64 + sc * 8, &As[buf][L * 8]);
        }
#pragma unroll
        for (int c = 0; c < BNT / 64; c++) {
            int L = c * 512 + tid;
            int row = L >> 3, s16 = L & 7;
            int sc = s16 ^ (row & 7);
            GLD_LDS16(g.BT + (size_t)(colbase + row) * DK + t * 64 + sc * 8, &Bs[buf][L * 8]);
        }
    };

    stage(0, 0);
    stage(1, 1);
    stage(2, 2);

    auto wait_vm = [&](int vm) __attribute__((always_inline)) {
        if (vm == 12)     asm volatile("s_waitcnt vmcnt(12)" ::: "memory");
        else if (vm == 8) asm volatile("s_waitcnt vmcnt(8)" ::: "memory");
        else if (vm == 6) asm volatile("s_waitcnt vmcnt(6)" ::: "memory");
        else if (vm == 4) asm volatile("s_waitcnt vmcnt(4)" ::: "memory");
        else              asm volatile("s_waitcnt vmcnt(0)" ::: "memory");
    };

    auto ktile = [&](int t, int cur, bool doStage, int vm) __attribute__((always_inline)) {
        wait_vm(vm);                                     // tile t's loads landed
        asm volatile("s_barrier" ::: "memory");          // tile t visible everywhere
        bf16x8 a0[4], b0[JN], a1[4], b1[JN];
#pragma unroll
        for (int i = 0; i < 4; i++)
            a0[i] = *(const bf16x8*)&As[cur][(wm + i * 16 + cl) * 64 + ((qd ^ (cl & 7)) * 8)];
#pragma unroll
        for (int j = 0; j < JN; j++)
            b0[j] = *(const bf16x8*)&Bs[cur][(wn + j * 16 + cl) * 64 + ((qd ^ (cl & 7)) * 8)];
#pragma unroll
        for (int i = 0; i < 4; i++)
            a1[i] = *(const bf16x8*)&As[cur][(wm + i * 16 + cl) * 64 + (((4 + qd) ^ (cl & 7)) * 8)];
#pragma unroll
        for (int j = 0; j < JN; j++)
            b1[j] = *(const bf16x8*)&Bs[cur][(wn + j * 16 + cl) * 64 + (((4 + qd) ^ (cl & 7)) * 8)];
        __builtin_amdgcn_s_setprio(1);
        if (swapped) {
#pragma unroll
            for (int i = 0; i < 4; i++)
#pragma unroll
                for (int j = 0; j < JN; j++)
                    acc[i][j] = __builtin_amdgcn_mfma_f32_16x16x32_bf16(b0[j], a0[i], acc[i][j], 0, 0, 0);
        } else {
#pragma unroll
            for (int i = 0; i < 4; i++)
#pragma unroll
                for (int j = 0; j < JN; j++)
                    acc[i][j] = __builtin_amdgcn_mfma_f32_16x16x32_bf16(a0[i], b0[j], acc[i][j], 0, 0, 0);
        }
        __builtin_amdgcn_s_setprio(0);
        asm volatile("s_waitcnt lgkmcnt(0)" ::: "memory");  // ALL reads of buf[cur] retired
        asm volatile("s_barrier" ::: "memory");             // buffer free for restage
        if (doStage) stage(t + 3, cur);                     // in flight during k1 MFMAs
        __builtin_amdgcn_s_setprio(1);
        if (swapped) {
#pragma unroll
            for (int i = 0; i < 4; i++)
#pragma unroll
                for (int j = 0; j < JN; j++)
                    acc[i][j] = __builtin_amdgcn_mfma_f32_16x16x32_bf16(b1[j], a1[i], acc[i][j], 0, 0, 0);
        } else {
#pragma unroll
            for (int i = 0; i < 4; i++)
#pragma unroll
                for (int j = 0; j < JN; j++)
                    acc[i][j] = __builtin_amdgcn_mfma_f32_16x16x32_bf16(a1[i], b1[j], acc[i][j], 0, 0, 0);
        }
        __builtin_amdgcn_s_setprio(0);
    };

    constexpr int STEADY = 2 * LOADS;
    // tiles 0..11 in buffer-static triples; stages reach tile 14
    for (int tt = 0; tt < 12; tt += 3) {
        ktile(tt + 0, 0, true, STEADY);
        ktile(tt + 1, 1, true, STEADY);
        ktile(tt + 2, 2, true, STEADY);
    }
    ktile(12, 0, true,  STEADY);   // stages tile 15 into buf 0
    ktile(13, 1, false, STEADY);   // outstanding after: tiles 14,15 = 2*LOADS
    ktile(14, 2, false, LOADS);    // outstanding after: tile 15 = LOADS
    ktile(15, 0, false, 0);

    if (g.mode == 2) {
        float* out = (float*)g.out;
#pragma unroll
        for (int i = 0; i < 4; i++)
#pragma unroll
            for (int j = 0; j < JN; j++)
#pragma unroll
                for (int r = 0; r < 4; r++) {
                    int row = rowbase + wm + i * 16 + qd * 4 + r;
                    int col = colbase + wn + j * 16 + cl;
                    out[(size_t)row * DK + col] = (acc[i][j][r] + g.bias[col]) * g.oscale;
                }
    } else if (g.mode == 0) {
        bf16* out = (bf16*)g.out;
#pragma unroll
        for (int i = 0; i < 4; i++)
#pragma unroll
            for (int j = 0; j < JN; j++)
#pragma unroll
                for (int r = 0; r < 4; r++) {
                    int row = rowbase + wm + i * 16 + qd * 4 + r;
                    int col = colbase + wn + j * 16 + cl;
                    float v = (acc[i][j][r] + g.bias[col]) * g.oscale;
                    out[(size_t)row * DK + col] = (bf16)v;
                }
    } else {
        // transposed epilogue: acc holds C^T tile — rows = cols(h,d), cols = rows(s)
        bf16* out = (bf16*)g.out;   // (B,H,64,S)
#pragma unroll
        for (int i = 0; i < 4; i++)
#pragma unroll
            for (int j = 0; j < JN; j++)
#pragma unroll
                for (int r = 0; r < 4; r++) {
                    int colg = colbase + wn + j * 16 + qd * 4 + r;   // h*64+d
                    int rowg = rowbase + wm + i * 16 + cl;           // b*2048+s
                    int b_ = rowg >> 11, s_ = rowg & 2047;
                    float v = (acc[i][j][r] + g.bias[colg]) * g.oscale;
                    out[((size_t)(b_ * NH + (colg >> 6)) * DH + (colg & 63)) * SSEQ + s_] = (bf16)v;
                }
    }
}

// ---------------------------------------------------------------- flash attention
// R10 version (measured 74.0us): grid 1024 (XCD-swizzled), 4 waves x 32 queries.
// S^T = K·Q^T via 16x16x32; KEY-PERMUTED K staging -> post-exp2 P fragments are
// directly the full-rate PV B-operand. Ones-MFMA softmax denominator (La) on
// the matrix pipe (VALU 50->44%); T5 setprio; bounds(256,3) — (256,4) spills.
__global__ __launch_bounds__(256, 3) void attn(const bf16* __restrict__ Qh,
                                               const bf16* __restrict__ Kh,
                                               const bf16* __restrict__ VTh,
                                               bf16* __restrict__ mrg) {
    __shared__ __attribute__((aligned(16))) bf16 Ks[2][64 * 64];   // [perm key][d], swizzled
    __shared__ __attribute__((aligned(16))) bf16 VTs[2][64 * 64];  // [d][key], swizzled
    const int tid = threadIdx.x;
    const int lane = tid & 63, w = tid >> 6;
    const int cl = lane & 15, qd = lane >> 4;
    // XCD swizzle: 8 bh values per XCD -> K/V working set = 4 MB = one L2
    const int F = blockIdx.x;            // 0..1023
    const int xcd = F & 7, slot = F >> 3;
    const int bh = xcd * 8 + (slot & 7);
    const int qt = slot >> 3;            // 0..15
    const int b_ = bh >> 4, h_ = bh & 15;
    const int qbase = qt * 128;
    const bf16* Qb = Qh + ((size_t)b_ * SSEQ) * DK + h_ * DH;   // row stride DK
    const bf16* Kb = Kh + ((size_t)b_ * SSEQ) * DK + h_ * DH;
    const bf16* Vb = VTh + (size_t)bh * DH * SSEQ;

    // Q fragments (B-operand of S^T): lane n=cl=query, k=d. Pre-scaled by log2(e)/8.
    bf16x8 qf[2][2];
#pragma unroll
    for (int mi = 0; mi < 2; mi++) {
        int q = qbase + w * 32 + mi * 16 + cl;
        qf[mi][0] = *(const bf16x8*)&Qb[(size_t)q * DK + qd * 8];
        qf[mi][1] = *(const bf16x8*)&Qb[(size_t)q * DK + 32 + qd * 8];
    }
    f32x4 O[2][4];   // O^T tiles: [query-tile][d-tile], lane: query=cl, d=qd*4+r
#pragma unroll
    for (int mi = 0; mi < 2; mi++)
#pragma unroll
        for (int jv = 0; jv < 4; jv++) O[mi][jv] = f32x4{0.f, 0.f, 0.f, 0.f};
    f32x4 La[2] = { f32x4{0.f, 0.f, 0.f, 0.f}, f32x4{0.f, 0.f, 0.f, 0.f} };
    bf16x8 ones8;
#pragma unroll
    for (int r = 0; r < 8; r++) ones8[r] = (bf16)1.0f;

    // stage tile kt into buffer buf. K rows permuted by pi; V unpermuted.
    auto stage = [&](int kt, int buf) {
#pragma unroll
        for (int c = 0; c < 2; c++) {
            int L = c * 256 + tid;
            int row = L >> 3, lc = (L & 7) ^ (row & 7);
            int prow = ((row >> 5) << 5) | (((row >> 2) & 3) << 3)
                     | (((row >> 4) & 1) << 2) | (row & 3);      // pi(row)
            GLD_LDS16(Kb + (size_t)(kt * 64 + prow) * DK + lc * 8, &Ks[buf][L * 8]);
        }
#pragma unroll
        for (int c = 0; c < 2; c++) {
            int L = c * 256 + tid;
            int row = L >> 3, lc = (L & 7) ^ (row & 7);
            GLD_LDS16(Vb + (size_t)row * SSEQ + kt * 64 + lc * 8, &VTs[buf][L * 8]);
        }
    };
    stage(0, 0);

    for (int kt = 0; kt < 32; kt++) {
        const int buf = kt & 1;
        __syncthreads();                 // tile kt staged; prev reads of buf^1 done
        if (kt + 1 < 32) stage(kt + 1, buf ^ 1);

        // S^T = K Q^T, exp2 -> P^T register fragments.
        // pf8[mi][g][ (jt&1)*4 + r ] = P[phys 32g+8qd+4*(jt&1)+r][query cl]
        bf16x8 pf8[2][2];
#pragma unroll
        for (int jt = 0; jt < 4; jt++) {
            bf16x8 kf0 = *(const bf16x8*)&Ks[buf][(jt * 16 + cl) * 64 + ((qd ^ (cl & 7)) * 8)];
            bf16x8 kf1 = *(const bf16x8*)&Ks[buf][(jt * 16 + cl) * 64 + (((4 + qd) ^ (cl & 7)) * 8)];
#pragma unroll
            for (int mi = 0; mi < 2; mi++) {
                __builtin_amdgcn_s_setprio(1);
                f32x4 S = __builtin_amdgcn_mfma_f32_16x16x32_bf16(kf0, qf[mi][0],
                                                                  f32x4{0.f, 0.f, 0.f, 0.f}, 0, 0, 0);
                S = __builtin_amdgcn_mfma_f32_16x16x32_bf16(kf1, qf[mi][1], S, 0, 0, 0);
                __builtin_amdgcn_s_setprio(0);
#pragma unroll
                for (int r = 0; r < 4; r++)
                    pf8[mi][jt >> 1][(jt & 1) * 4 + r] = (bf16)__builtin_amdgcn_exp2f(S[r]);
            }
        }

        // O^T += V^T P^T; l += ones·P^T (denominator on the matrix pipe)
        __builtin_amdgcn_s_setprio(1);
#pragma unroll
        for (int g = 0; g < 2; g++) {
#pragma unroll
            for (int jv = 0; jv < 4; jv++) {
                bf16x8 vf = *(const bf16x8*)&VTs[buf][(jv * 16 + cl) * 64 +
                                (((g * 4 + qd) ^ (cl & 7)) * 8)];
#pragma unroll
                for (int mi = 0; mi < 2; mi++)
                    O[mi][jv] = __builtin_amdgcn_mfma_f32_16x16x32_bf16(vf, pf8[mi][g], O[mi][jv], 0, 0, 0);
            }
#pragma unroll
            for (int mi = 0; mi < 2; mi++)
                La[mi] = __builtin_amdgcn_mfma_f32_16x16x32_bf16(ones8, pf8[mi][g], La[mi], 0, 0, 0);
        }
        __builtin_amdgcn_s_setprio(0);
    }

    // epilogue: every lane already holds l(query cl) in La[mi][0] — no shfl.
#pragma unroll
    for (int mi = 0; mi < 2; mi++) {
        float inv = 1.0f / La[mi][0];
        int q = qbase + w * 32 + mi * 16 + cl;
        size_t ro = ((size_t)(b_ * SSEQ + q)) * DK + h_ * DH;
#pragma unroll
        for (int jv = 0; jv < 4; jv++) {
            bf16x4 o4;
#pragma unroll
            for (int r = 0; r < 4; r++) o4[r] = (bf16)(O[mi][jv][r] * inv);
            *(bf16x4*)&mrg[ro + jv * 16 + qd * 4] = o4;
        }
    }
}

// ---------------------------------------------------------------- launch
extern "C" void kernel_launch(void* const* d_in, const int* in_sizes, int n_in,
                              void* d_out, int out_size, void* d_ws, size_t ws_size,
                              hipStream_t stream) {
    const float* q  = (const float*)d_in[0];
    const float* k  = (const float*)d_in[1];
    const float* v  = (const float*)d_in[2];
    const float* Wq = (const float*)d_in[3];
    const float* bq = (const float*)d_in[4];
    const float* Wk = (const float*)d_in[5];
    const float* bk = (const float*)d_in[6];
    const float* Wv = (const float*)d_in[7];
    const float* bv = (const float*)d_in[8];
    const float* Wu = (const float*)d_in[9];
    const float* bu = (const float*)d_in[10];
    char* ws = (char*)d_ws;
    bf16* qbf = (bf16*)(ws + OFF_QBF);
    bf16* kbf = (bf16*)(ws + OFF_KBF);
    bf16* vbf = (bf16*)(ws + OFF_VBF);
    bf16* wqt = (bf16*)(ws + OFF_WQT);
    bf16* wkt = (bf16*)(ws + OFF_WKT);
    bf16* wvt = (bf16*)(ws + OFF_WVT);
    bf16* wut = (bf16*)(ws + OFF_WUT);
    bf16* qh  = (bf16*)(ws + OFF_QH);
    bf16* kh  = (bf16*)(ws + OFF_KH);
    bf16* vth = (bf16*)(ws + OFF_VTH);
    bf16* mrg = (bf16*)(ws + OFF_MRG);

    cvt_x<<<dim3(8192, 1, 3), 256, 0, stream>>>(q, k, v, qbf, kbf, vbf);
    cvt_wT<<<dim3(16, 16, 4), 256, 0, stream>>>(Wq, Wk, Wv, Wu, wqt, wkt, wvt, wut);

    // Q projection folds score scale AND log2(e) for exp2-softmax: 0.125 * log2(e)
    GArg gq{qbf, wqt, bq, (void*)qh, 0, 0.18033688011112043f};
    GArg gk{kbf, wkt, bk, (void*)kh, 0, 1.0f};
    GArg gv{vbf, wvt, bv, (void*)vth, 1, 1.0f};
    gemm_bt<256><<<dim3(256, 1, 3), 512, 0, stream>>>(gq, gk, gv);

    attn<<<dim3(1024), 256, 0, stream>>>(qh, kh, vth, mrg);

    GArg go{mrg, wut, bu, d_out, 2, 1.0f};
    gemm_bt<128><<<dim3(512, 1, 1), 512, 0, stream>>>(go, go, go);
}

// Round 13
// 310.505 us; speedup vs baseline: 1.1001x; 1.0770x over previous
//
#include <hip/hip_runtime.h>

typedef __bf16 bf16;
typedef __bf16 bf16x8 __attribute__((ext_vector_type(8)));
typedef __bf16 bf16x4 __attribute__((ext_vector_type(4)));
typedef float  f32x4  __attribute__((ext_vector_type(4)));

#define GLD_LDS16(gp, lp) __builtin_amdgcn_global_load_lds( \
    (const __attribute__((address_space(1))) unsigned int*)(const void*)(gp), \
    (__attribute__((address_space(3))) unsigned int*)(void*)(lp), 16, 0, 0)

constexpr int BB = 4, SSEQ = 2048, DK = 1024, NH = 16, DH = 64;
constexpr int M = BB * SSEQ;                    // 8192 rows

constexpr size_t SZ_X = (size_t)M * DK * 2;     // 16 MiB
constexpr size_t SZ_W = (size_t)DK * DK * 2;    // 2 MiB
constexpr size_t OFF_QBF = 0;
constexpr size_t OFF_KBF = OFF_QBF + SZ_X;
constexpr size_t OFF_VBF = OFF_KBF + SZ_X;
constexpr size_t OFF_WQT = OFF_VBF + SZ_X;
constexpr size_t OFF_WKT = OFF_WQT + SZ_W;
constexpr size_t OFF_WVT = OFF_WKT + SZ_W;
constexpr size_t OFF_WUT = OFF_WVT + SZ_W;
constexpr size_t OFF_QH  = OFF_WUT + SZ_W;      // (B,S,1024) bf16 flat
constexpr size_t OFF_KH  = OFF_QH + SZ_X;       // (B,S,1024) bf16 flat
constexpr size_t OFF_VTH = OFF_KH + SZ_X;       // (B,H,64,S) bf16 (transposed)
constexpr size_t OFF_MRG = OFF_VTH + SZ_X;      // (B,S,1024) bf16

// ---------------------------------------------------------------- converts
// R13: cvt_x and cvt_wT merged into ONE launch (pipeline shows ~20us per
// launch boundary; 5 launches -> 4). Blocks 0..24575: x-convert (z = bid>>13);
// blocks 24576..25599: weight transpose (wid = bid-24576).
__global__ void cvt_all(const float* __restrict__ q, const float* __restrict__ k,
                        const float* __restrict__ v,
                        const float* __restrict__ wq, const float* __restrict__ wk,
                        const float* __restrict__ wv, const float* __restrict__ wu,
                        bf16* __restrict__ qb, bf16* __restrict__ kb, bf16* __restrict__ vb,
                        bf16* __restrict__ wqt, bf16* __restrict__ wkt,
                        bf16* __restrict__ wvt, bf16* __restrict__ wut) {
    __shared__ float t[64][65];
    const int bid = blockIdx.x;
    if (bid < 24576) {
        const int z = bid >> 13;                 // 0..2
        const float* s = (z == 0) ? q : (z == 1) ? k : v;
        bf16*        d = (z == 0) ? qb : (z == 1) ? kb : vb;
        size_t i = (size_t)(bid & 8191) * blockDim.x + threadIdx.x;
        float4 val = ((const float4*)s)[i];
        bf16x4 o = { (bf16)val.x, (bf16)val.y, (bf16)val.z, (bf16)val.w };
        ((bf16x4*)d)[i] = o;
    } else {
        const int wid = bid - 24576;             // 0..1023
        const int z = wid >> 8;                  // 0..3
        const int r_ = wid & 255;
        const int by = (r_ >> 4) * 64, bx = (r_ & 15) * 64;
        const float* w = (z == 0) ? wq : (z == 1) ? wk : (z == 2) ? wv : wu;
        bf16* o        = (z == 0) ? wqt : (z == 1) ? wkt : (z == 2) ? wvt : wut;
        int tx = threadIdx.x & 63, ty = threadIdx.x >> 6;
#pragma unroll
        for (int rr = 0; rr < 16; rr++) {
            int row = ty * 16 + rr;
            t[row][tx] = w[(size_t)(by + row) * DK + bx + tx];
        }
        __syncthreads();
#pragma unroll
        for (int rr = 0; rr < 16; rr++) {
            int row2 = ty * 16 + rr;
            o[(size_t)(bx + row2) * DK + by + tx] = (bf16)t[tx][row2];
        }
    }
}

// ---------------------------------------------------------------- GEMM (C = A @ BT^T + bias)
// R7 schedule (verified race-free): 8-wave 128xBN x64 tile, raw s_barrier +
// counted vmcnt (T3+T4), T2 XOR-swizzle via pre-swizzled global source, T5
// setprio. Sync: BAR1 after counted vmcnt: tile t landed. BAR2 after lgkm(0):
// all reads of buf[cur] retired -> stage(t+2) may overwrite.
// R12 LESSON: triple-buffer spilled ~16 regs (WRITE 49->74MB) — 2 buffers only.
// R13: QKV also BN=128 (was 256): LDS 64KB -> 2 blocks/CU; cross-block TLP
// covers the barrier waits (m97's mechanism: ~3 resident blocks = 874 TF).
// Grid 512/z = 2 blocks/CU x 3 rounds (QKV), x 1 round (proj). Per-XCD
// working set unchanged (A 2MB + B 2MB). LOADS=4 -> vmcnt(4).
// mode 0: out bf16 row-major; mode 1: out bf16 (B,H,64,S); mode 2: out f32
struct GArg {
    const bf16* A; const bf16* BT; const float* bias; void* out; int mode; float oscale;
};

template<int BNT>
__global__ __launch_bounds__(512, 2) void gemm_bt(GArg g0, GArg g1, GArg g2) {
    GArg g;
    if (blockIdx.z == 0) g = g0; else if (blockIdx.z == 1) g = g1; else g = g2;
    constexpr int JN = BNT / 64;                  // per-wave 16-col tiles (4 or 2)
    __shared__ __attribute__((aligned(16))) bf16 As[2][128 * 64];
    __shared__ __attribute__((aligned(16))) bf16 Bs[2][BNT * 64];
    const int tid = threadIdx.x;                 // 0..511
    const int lane = tid & 63, wv = tid >> 6;    // 8 waves
    const int wm = (wv >> 2) * 64;               // 0,64   (2 row-groups)
    const int wn = (wv & 3) * (BNT / 4);         // 4 col-groups
    const int cl = lane & 15, qd = lane >> 4;
    const int x = (int)blockIdx.x;
    const int rowbase = ((x & 7) * 8 + ((x >> 3) & 7)) * 128;
    const int colbase = (x >> 6) * BNT;

    f32x4 acc[4][JN];
#pragma unroll
    for (int i = 0; i < 4; i++)
#pragma unroll
        for (int j = 0; j < JN; j++) acc[i][j] = f32x4{0.f, 0.f, 0.f, 0.f};

    const bool swapped = (g.mode == 1);

    auto stage = [&](int t, int buf) {
#pragma unroll
        for (int c = 0; c < 2; c++) {
            int L = c * 512 + tid;
            int row = L >> 3, s16 = L & 7;
            int sc = s16 ^ (row & 7);
            GLD_LDS16(g.A + (size_t)(rowbase + row) * DK + t * 64 + sc * 8, &As[buf][L * 8]);
        }
#pragma unroll
        for (int c = 0; c < BNT / 64; c++) {
            int L = c * 512 + tid;
            int row = L >> 3, s16 = L & 7;
            int sc = s16 ^ (row & 7);
            GLD_LDS16(g.BT + (size_t)(colbase + row) * DK + t * 64 + sc * 8, &Bs[buf][L * 8]);
        }
    };

    stage(0, 0);
    stage(1, 1);

    auto ktile = [&](int t, int cur, bool doStage, bool last) __attribute__((always_inline)) {
        if (last) asm volatile("s_waitcnt vmcnt(0)" ::: "memory");
        else if constexpr (BNT == 256) asm volatile("s_waitcnt vmcnt(6)" ::: "memory");
        else                           asm volatile("s_waitcnt vmcnt(4)" ::: "memory");
        asm volatile("s_barrier" ::: "memory");          // tile t visible everywhere
        bf16x8 a0[4], b0[JN], a1[4], b1[JN];
#pragma unroll
        for (int i = 0; i < 4; i++)
            a0[i] = *(const bf16x8*)&As[cur][(wm + i * 16 + cl) * 64 + ((qd ^ (cl & 7)) * 8)];
#pragma unroll
        for (int j = 0; j < JN; j++)
            b0[j] = *(const bf16x8*)&Bs[cur][(wn + j * 16 + cl) * 64 + ((qd ^ (cl & 7)) * 8)];
#pragma unroll
        for (int i = 0; i < 4; i++)
            a1[i] = *(const bf16x8*)&As[cur][(wm + i * 16 + cl) * 64 + (((4 + qd) ^ (cl & 7)) * 8)];
#pragma unroll
        for (int j = 0; j < JN; j++)
            b1[j] = *(const bf16x8*)&Bs[cur][(wn + j * 16 + cl) * 64 + (((4 + qd) ^ (cl & 7)) * 8)];
        __builtin_amdgcn_s_setprio(1);
        if (swapped) {
#pragma unroll
            for (int i = 0; i < 4; i++)
#pragma unroll
                for (int j = 0; j < JN; j++)
                    acc[i][j] = __builtin_amdgcn_mfma_f32_16x16x32_bf16(b0[j], a0[i], acc[i][j], 0, 0, 0);
        } else {
#pragma unroll
            for (int i = 0; i < 4; i++)
#pragma unroll
                for (int j = 0; j < JN; j++)
                    acc[i][j] = __builtin_amdgcn_mfma_f32_16x16x32_bf16(a0[i], b0[j], acc[i][j], 0, 0, 0);
        }
        __builtin_amdgcn_s_setprio(0);
        asm volatile("s_waitcnt lgkmcnt(0)" ::: "memory");  // ALL reads of buf[cur] retired
        asm volatile("s_barrier" ::: "memory");             // buffer free for restage
        if (doStage) stage(t + 2, cur);                     // in flight during k1 MFMAs
        __builtin_amdgcn_s_setprio(1);
        if (swapped) {
#pragma unroll
            for (int i = 0; i < 4; i++)
#pragma unroll
                for (int j = 0; j < JN; j++)
                    acc[i][j] = __builtin_amdgcn_mfma_f32_16x16x32_bf16(b1[j], a1[i], acc[i][j], 0, 0, 0);
        } else {
#pragma unroll
            for (int i = 0; i < 4; i++)
#pragma unroll
                for (int j = 0; j < JN; j++)
                    acc[i][j] = __builtin_amdgcn_mfma_f32_16x16x32_bf16(a1[i], b1[j], acc[i][j], 0, 0, 0);
        }
        __builtin_amdgcn_s_setprio(0);
    };

    for (int t = 0; t < 14; ++t) ktile(t, t & 1, true, false);
    ktile(14, 0, false, false);
    ktile(15, 1, false, true);

    if (g.mode == 2) {
        float* out = (float*)g.out;
#pragma unroll
        for (int i = 0; i < 4; i++)
#pragma unroll
            for (int j = 0; j < JN; j++)
#pragma unroll
                for (int r = 0; r < 4; r++) {
                    int row = rowbase + wm + i * 16 + qd * 4 + r;
                    int col = colbase + wn + j * 16 + cl;
                    out[(size_t)row * DK + col] = (acc[i][j][r] + g.bias[col]) * g.oscale;
                }
    } else if (g.mode == 0) {
        bf16* out = (bf16*)g.out;
#pragma unroll
        for (int i = 0; i < 4; i++)
#pragma unroll
            for (int j = 0; j < JN; j++)
#pragma unroll
                for (int r = 0; r < 4; r++) {
                    int row = rowbase + wm + i * 16 + qd * 4 + r;
                    int col = colbase + wn + j * 16 + cl;
                    float v = (acc[i][j][r] + g.bias[col]) * g.oscale;
                    out[(size_t)row * DK + col] = (bf16)v;
                }
    } else {
        // transposed epilogue: acc holds C^T tile — rows = cols(h,d), cols = rows(s)
        bf16* out = (bf16*)g.out;   // (B,H,64,S)
#pragma unroll
        for (int i = 0; i < 4; i++)
#pragma unroll
            for (int j = 0; j < JN; j++)
#pragma unroll
                for (int r = 0; r < 4; r++) {
                    int colg = colbase + wn + j * 16 + qd * 4 + r;   // h*64+d
                    int rowg = rowbase + wm + i * 16 + cl;           // b*2048+s
                    int b_ = rowg >> 11, s_ = rowg & 2047;
                    float v = (acc[i][j][r] + g.bias[colg]) * g.oscale;
                    out[((size_t)(b_ * NH + (colg >> 6)) * DH + (colg & 63)) * SSEQ + s_] = (bf16)v;
                }
    }
}

// ---------------------------------------------------------------- flash attention
// R10 version (measured 74.0us): grid 1024 (XCD-swizzled), 4 waves x 32 queries.
// S^T = K·Q^T via 16x16x32; KEY-PERMUTED K staging -> post-exp2 P fragments are
// directly the full-rate PV B-operand. Ones-MFMA softmax denominator (La) on
// the matrix pipe (VALU 50->44%); T5 setprio; bounds(256,3) — (256,4) spills.
__global__ __launch_bounds__(256, 3) void attn(const bf16* __restrict__ Qh,
                                               const bf16* __restrict__ Kh,
                                               const bf16* __restrict__ VTh,
                                               bf16* __restrict__ mrg) {
    __shared__ __attribute__((aligned(16))) bf16 Ks[2][64 * 64];   // [perm key][d], swizzled
    __shared__ __attribute__((aligned(16))) bf16 VTs[2][64 * 64];  // [d][key], swizzled
    const int tid = threadIdx.x;
    const int lane = tid & 63, w = tid >> 6;
    const int cl = lane & 15, qd = lane >> 4;
    // XCD swizzle: 8 bh values per XCD -> K/V working set = 4 MB = one L2
    const int F = blockIdx.x;            // 0..1023
    const int xcd = F & 7, slot = F >> 3;
    const int bh = xcd * 8 + (slot & 7);
    const int qt = slot >> 3;            // 0..15
    const int b_ = bh >> 4, h_ = bh & 15;
    const int qbase = qt * 128;
    const bf16* Qb = Qh + ((size_t)b_ * SSEQ) * DK + h_ * DH;   // row stride DK
    const bf16* Kb = Kh + ((size_t)b_ * SSEQ) * DK + h_ * DH;
    const bf16* Vb = VTh + (size_t)bh * DH * SSEQ;

    // Q fragments (B-operand of S^T): lane n=cl=query, k=d. Pre-scaled by log2(e)/8.
    bf16x8 qf[2][2];
#pragma unroll
    for (int mi = 0; mi < 2; mi++) {
        int q = qbase + w * 32 + mi * 16 + cl;
        qf[mi][0] = *(const bf16x8*)&Qb[(size_t)q * DK + qd * 8];
        qf[mi][1] = *(const bf16x8*)&Qb[(size_t)q * DK + 32 + qd * 8];
    }
    f32x4 O[2][4];   // O^T tiles: [query-tile][d-tile], lane: query=cl, d=qd*4+r
#pragma unroll
    for (int mi = 0; mi < 2; mi++)
#pragma unroll
        for (int jv = 0; jv < 4; jv++) O[mi][jv] = f32x4{0.f, 0.f, 0.f, 0.f};
    f32x4 La[2] = { f32x4{0.f, 0.f, 0.f, 0.f}, f32x4{0.f, 0.f, 0.f, 0.f} };
    bf16x8 ones8;
#pragma unroll
    for (int r = 0; r < 8; r++) ones8[r] = (bf16)1.0f;

    // stage tile kt into buffer buf. K rows permuted by pi; V unpermuted.
    auto stage = [&](int kt, int buf) {
#pragma unroll
        for (int c = 0; c < 2; c++) {
            int L = c * 256 + tid;
            int row = L >> 3, lc = (L & 7) ^ (row & 7);
            int prow = ((row >> 5) << 5) | (((row >> 2) & 3) << 3)
                     | (((row >> 4) & 1) << 2) | (row & 3);      // pi(row)
            GLD_LDS16(Kb + (size_t)(kt * 64 + prow) * DK + lc * 8, &Ks[buf][L * 8]);
        }
#pragma unroll
        for (int c = 0; c < 2; c++) {
            int L = c * 256 + tid;
            int row = L >> 3, lc = (L & 7) ^ (row & 7);
            GLD_LDS16(Vb + (size_t)row * SSEQ + kt * 64 + lc * 8, &VTs[buf][L * 8]);
        }
    };
    stage(0, 0);

    for (int kt = 0; kt < 32; kt++) {
        const int buf = kt & 1;
        __syncthreads();                 // tile kt staged; prev reads of buf^1 done
        if (kt + 1 < 32) stage(kt + 1, buf ^ 1);

        // S^T = K Q^T, exp2 -> P^T register fragments.
        // pf8[mi][g][ (jt&1)*4 + r ] = P[phys 32g+8qd+4*(jt&1)+r][query cl]
        bf16x8 pf8[2][2];
#pragma unroll
        for (int jt = 0; jt < 4; jt++) {
            bf16x8 kf0 = *(const bf16x8*)&Ks[buf][(jt * 16 + cl) * 64 + ((qd ^ (cl & 7)) * 8)];
            bf16x8 kf1 = *(const bf16x8*)&Ks[buf][(jt * 16 + cl) * 64 + (((4 + qd) ^ (cl & 7)) * 8)];
#pragma unroll
            for (int mi = 0; mi < 2; mi++) {
                __builtin_amdgcn_s_setprio(1);
                f32x4 S = __builtin_amdgcn_mfma_f32_16x16x32_bf16(kf0, qf[mi][0],
                                                                  f32x4{0.f, 0.f, 0.f, 0.f}, 0, 0, 0);
                S = __builtin_amdgcn_mfma_f32_16x16x32_bf16(kf1, qf[mi][1], S, 0, 0, 0);
                __builtin_amdgcn_s_setprio(0);
#pragma unroll
                for (int r = 0; r < 4; r++)
                    pf8[mi][jt >> 1][(jt & 1) * 4 + r] = (bf16)__builtin_amdgcn_exp2f(S[r]);
            }
        }

        // O^T += V^T P^T; l += ones·P^T (denominator on the matrix pipe)
        __builtin_amdgcn_s_setprio(1);
#pragma unroll
        for (int g = 0; g < 2; g++) {
#pragma unroll
            for (int jv = 0; jv < 4; jv++) {
                bf16x8 vf = *(const bf16x8*)&VTs[buf][(jv * 16 + cl) * 64 +
                                (((g * 4 + qd) ^ (cl & 7)) * 8)];
#pragma unroll
                for (int mi = 0; mi < 2; mi++)
                    O[mi][jv] = __builtin_amdgcn_mfma_f32_16x16x32_bf16(vf, pf8[mi][g], O[mi][jv], 0, 0, 0);
            }
#pragma unroll
            for (int mi = 0; mi < 2; mi++)
                La[mi] = __builtin_amdgcn_mfma_f32_16x16x32_bf16(ones8, pf8[mi][g], La[mi], 0, 0, 0);
        }
        __builtin_amdgcn_s_setprio(0);
    }

    // epilogue: every lane already holds l(query cl) in La[mi][0] — no shfl.
#pragma unroll
    for (int mi = 0; mi < 2; mi++) {
        float inv = 1.0f / La[mi][0];
        int q = qbase + w * 32 + mi * 16 + cl;
        size_t ro = ((size_t)(b_ * SSEQ + q)) * DK + h_ * DH;
#pragma unroll
        for (int jv = 0; jv < 4; jv++) {
            bf16x4 o4;
#pragma unroll
            for (int r = 0; r < 4; r++) o4[r] = (bf16)(O[mi][jv][r] * inv);
            *(bf16x4*)&mrg[ro + jv * 16 + qd * 4] = o4;
        }
    }
}

// ---------------------------------------------------------------- launch
extern "C" void kernel_launch(void* const* d_in, const int* in_sizes, int n_in,
                              void* d_out, int out_size, void* d_ws, size_t ws_size,
                              hipStream_t stream) {
    const float* q  = (const float*)d_in[0];
    const float* k  = (const float*)d_in[1];
    const float* v  = (const float*)d_in[2];
    const float* Wq = (const float*)d_in[3];
    const float* bq = (const float*)d_in[4];
    const float* Wk = (const float*)d_in[5];
    const float* bk = (const float*)d_in[6];
    const float* Wv = (const float*)d_in[7];
    const float* bv = (const float*)d_in[8];
    const float* Wu = (const float*)d_in[9];
    const float* bu = (const float*)d_in[10];
    char* ws = (char*)d_ws;
    bf16* qbf = (bf16*)(ws + OFF_QBF);
    bf16* kbf = (bf16*)(ws + OFF_KBF);
    bf16* vbf = (bf16*)(ws + OFF_VBF);
    bf16* wqt = (bf16*)(ws + OFF_WQT);
    bf16* wkt = (bf16*)(ws + OFF_WKT);
    bf16* wvt = (bf16*)(ws + OFF_WVT);
    bf16* wut = (bf16*)(ws + OFF_WUT);
    bf16* qh  = (bf16*)(ws + OFF_QH);
    bf16* kh  = (bf16*)(ws + OFF_KH);
    bf16* vth = (bf16*)(ws + OFF_VTH);
    bf16* mrg = (bf16*)(ws + OFF_MRG);

    cvt_all<<<dim3(25600), 256, 0, stream>>>(q, k, v, Wq, Wk, Wv, Wu,
                                             qbf, kbf, vbf, wqt, wkt, wvt, wut);

    // Q projection folds score scale AND log2(e) for exp2-softmax: 0.125 * log2(e)
    GArg gq{qbf, wqt, bq, (void*)qh, 0, 0.18033688011112043f};
    GArg gk{kbf, wkt, bk, (void*)kh, 0, 1.0f};
    GArg gv{vbf, wvt, bv, (void*)vth, 1, 1.0f};
    gemm_bt<128><<<dim3(512, 1, 3), 512, 0, stream>>>(gq, gk, gv);

    attn<<<dim3(1024), 256, 0, stream>>>(qh, kh, vth, mrg);

    GArg go{mrg, wut, bu, d_out, 2, 1.0f};
    gemm_bt<128><<<dim3(512, 1, 1), 512, 0, stream>>>(go, go, go);
}